// Round 1
// baseline (75.230 us; speedup 1.0000x reference)
//
#include <hip/hip_runtime.h>
#include <math.h>

#define BATCH 4
#define NTOK 4096
#define ATTN_D 16
#define BLOCK 256
#define ROWS_PER_BLOCK 32            // rows of one batch handled per block
#define ROWS_PER_WAVE 8              // 4 waves/block * 8 = 32
#define CHUNKS_PER_BATCH (NTOK / ROWS_PER_BLOCK)   // 128
#define GRID (BATCH * CHUNKS_PER_BATCH)            // 512

__global__ __launch_bounds__(BLOCK) void attn_collapsed_kernel(
    const float* __restrict__ x,     // [B, N]
    const float* __restrict__ wq,    // [16]
    const float* __restrict__ wk,    // [16]
    const float* __restrict__ wv,    // [16]
    const float* __restrict__ wout,  // [16]
    float* __restrict__ out)         // [B, N]
{
    __shared__ float sx[NTOK];       // 16 KB: x[b, :]
    __shared__ float sred[8];        // per-wave max (0..3) / min (4..7)

    const int tid  = threadIdx.x;
    const int lane = tid & 63;
    const int wave = tid >> 6;
    const int b     = blockIdx.x >> 7;        // / CHUNKS_PER_BATCH
    const int chunk = blockIdx.x & 127;       // % CHUNKS_PER_BATCH

    const float* xb = x + b * NTOK;

    // ---- stage x[b,:] into LDS (float4, coalesced), tracking max/min ----
    float vmax = -INFINITY, vmin = INFINITY;
    const float4* x4 = (const float4*)xb;
    float4* s4 = (float4*)sx;
    #pragma unroll
    for (int i = 0; i < NTOK / 4 / BLOCK; ++i) {   // 4 iterations
        float4 v = x4[tid + i * BLOCK];
        s4[tid + i * BLOCK] = v;
        vmax = fmaxf(vmax, fmaxf(fmaxf(v.x, v.y), fmaxf(v.z, v.w)));
        vmin = fminf(vmin, fminf(fminf(v.x, v.y), fminf(v.z, v.w)));
    }
    // wave reduce max/min
    #pragma unroll
    for (int off = 32; off > 0; off >>= 1) {
        vmax = fmaxf(vmax, __shfl_xor(vmax, off));
        vmin = fminf(vmin, __shfl_xor(vmin, off));
    }
    if (lane == 0) { sred[wave] = vmax; sred[4 + wave] = vmin; }
    __syncthreads();
    vmax = fmaxf(fmaxf(sred[0], sred[1]), fmaxf(sred[2], sred[3]));
    vmin = fminf(fminf(sred[4], sred[5]), fminf(sred[6], sred[7]));

    // ---- collapsed weight dots (broadcast loads, redundant per thread) ----
    float cqk = 0.f, cvo = 0.f;
    #pragma unroll
    for (int d = 0; d < ATTN_D; ++d) {
        cqk = fmaf(wq[d], wk[d], cqk);
        cvo = fmaf(wv[d], wout[d], cvo);
    }

    const float LOG2E = 1.4426950408889634f;
    const int row0 = chunk * ROWS_PER_BLOCK + wave * ROWS_PER_WAVE;

    // per-row scalars (base-2 domain): e^(a*xm - M) = 2^(a2*xm - M2)
    float a2[ROWS_PER_WAVE], M2[ROWS_PER_WAVE];
    float S0[ROWS_PER_WAVE], S1[ROWS_PER_WAVE];
    #pragma unroll
    for (int r = 0; r < ROWS_PER_WAVE; ++r) {
        float xr = sx[row0 + r];                 // LDS broadcast
        float an = 0.25f * cqk * xr;             // scale=1/sqrt(16), tau=1
        float Mn = (an >= 0.f) ? an * vmax : an * vmin;  // row max of an*xm
        a2[r] = an * LOG2E;
        M2[r] = Mn * LOG2E;
        S0[r] = 0.f;
        S1[r] = 0.f;
    }

    // ---- main loop: 64 iters/lane, 8 rows share each ds_read ----
    for (int i = lane; i < NTOK; i += 64) {
        float xm = sx[i];
        #pragma unroll
        for (int r = 0; r < ROWS_PER_WAVE; ++r) {
            float e = __builtin_amdgcn_exp2f(fmaf(a2[r], xm, -M2[r]));
            S0[r] += e;
            S1[r] = fmaf(xm, e, S1[r]);
        }
    }

    // ---- wave reduction per row, lane 0 writes ----
    #pragma unroll
    for (int r = 0; r < ROWS_PER_WAVE; ++r) {
        float s0 = S0[r], s1 = S1[r];
        #pragma unroll
        for (int off = 32; off > 0; off >>= 1) {
            s0 += __shfl_xor(s0, off);
            s1 += __shfl_xor(s1, off);
        }
        if (lane == 0) out[b * NTOK + row0 + r] = cvo * (s1 / s0);
    }
}

extern "C" void kernel_launch(void* const* d_in, const int* in_sizes, int n_in,
                              void* d_out, int out_size, void* d_ws, size_t ws_size,
                              hipStream_t stream) {
    const float* x    = (const float*)d_in[0];
    const float* wq   = (const float*)d_in[1];
    const float* wk   = (const float*)d_in[2];
    const float* wv   = (const float*)d_in[3];
    const float* wout = (const float*)d_in[4];
    float* out = (float*)d_out;

    attn_collapsed_kernel<<<dim3(GRID), dim3(BLOCK), 0, stream>>>(
        x, wq, wk, wv, wout, out);
}

// Round 2
// 70.705 us; speedup vs baseline: 1.0640x; 1.0640x over previous
//
#include <hip/hip_runtime.h>
#include <math.h>

#define BATCH 4
#define NTOK 4096
#define ATTN_D 16
#define BLOCK 256
#define ROWS_PER_WAVE 4                               // 4 rows per wave
#define ROWS_PER_BLOCK 16                             // 4 waves * 4 rows
#define CHUNKS_PER_BATCH (NTOK / ROWS_PER_BLOCK)      // 256
#define GRID (BATCH * CHUNKS_PER_BATCH)               // 1024 -> 4 waves/SIMD

__global__ __launch_bounds__(BLOCK) void attn_collapsed_kernel(
    const float* __restrict__ x,     // [B, N]
    const float* __restrict__ wq,    // [16]
    const float* __restrict__ wk,    // [16]
    const float* __restrict__ wv,    // [16]
    const float* __restrict__ wout,  // [16]
    float* __restrict__ out)         // [B, N]
{
    __shared__ float sx[NTOK];       // 16 KB: x[b, :]
    __shared__ float sred[8];        // per-wave max (0..3) / min (4..7)

    const int tid  = threadIdx.x;
    const int lane = tid & 63;
    const int wave = tid >> 6;
    const int b     = blockIdx.x >> 8;        // / CHUNKS_PER_BATCH
    const int chunk = blockIdx.x & 255;       // % CHUNKS_PER_BATCH

    const float* xb = x + b * NTOK;

    // ---- stage x[b,:] into LDS (float4, coalesced), tracking max/min ----
    float vmax = -INFINITY, vmin = INFINITY;
    const float4* x4 = (const float4*)xb;
    float4* s4 = (float4*)sx;
    #pragma unroll
    for (int i = 0; i < NTOK / 4 / BLOCK; ++i) {   // 4 iterations
        float4 v = x4[tid + i * BLOCK];
        s4[tid + i * BLOCK] = v;
        vmax = fmaxf(vmax, fmaxf(fmaxf(v.x, v.y), fmaxf(v.z, v.w)));
        vmin = fminf(vmin, fminf(fminf(v.x, v.y), fminf(v.z, v.w)));
    }
    // wave reduce max/min
    #pragma unroll
    for (int off = 32; off > 0; off >>= 1) {
        vmax = fmaxf(vmax, __shfl_xor(vmax, off));
        vmin = fminf(vmin, __shfl_xor(vmin, off));
    }
    if (lane == 0) { sred[wave] = vmax; sred[4 + wave] = vmin; }
    __syncthreads();
    vmax = fmaxf(fmaxf(sred[0], sred[1]), fmaxf(sred[2], sred[3]));
    vmin = fminf(fminf(sred[4], sred[5]), fminf(sred[6], sred[7]));

    // ---- collapsed weight dots (broadcast loads, redundant per thread) ----
    float cqk = 0.f, cvo = 0.f;
    #pragma unroll
    for (int d = 0; d < ATTN_D; ++d) {
        cqk = fmaf(wq[d], wk[d], cqk);
        cvo = fmaf(wv[d], wout[d], cvo);
    }

    const float LOG2E = 1.4426950408889634f;
    const int row0 = chunk * ROWS_PER_BLOCK + wave * ROWS_PER_WAVE;

    // per-row scalars (base-2 domain): e^(a*xm - M) = 2^(a2*xm - M2)
    float a2[ROWS_PER_WAVE], M2[ROWS_PER_WAVE];
    float S0[ROWS_PER_WAVE], S1[ROWS_PER_WAVE];
    #pragma unroll
    for (int r = 0; r < ROWS_PER_WAVE; ++r) {
        float xr = sx[row0 + r];                 // LDS broadcast
        float an = 0.25f * cqk * xr;             // scale=1/sqrt(16), tau=1
        float Mn = (an >= 0.f) ? an * vmax : an * vmin;  // row max of an*xm
        a2[r] = an * LOG2E;
        M2[r] = Mn * LOG2E;
        S0[r] = 0.f;
        S1[r] = 0.f;
    }

    // ---- main loop: ds_read_b128 feeds 4 m-values x 4 rows ----
    #pragma unroll 4
    for (int i = 0; i < NTOK / 4 / 64; ++i) {    // 16 iterations
        float4 xm4 = s4[lane + i * 64];
        #pragma unroll
        for (int c = 0; c < 4; ++c) {
            float xm = (c == 0) ? xm4.x : (c == 1) ? xm4.y : (c == 2) ? xm4.z : xm4.w;
            #pragma unroll
            for (int r = 0; r < ROWS_PER_WAVE; ++r) {
                float e = __builtin_amdgcn_exp2f(fmaf(a2[r], xm, -M2[r]));
                S0[r] += e;
                S1[r] = fmaf(xm, e, S1[r]);
            }
        }
    }

    // ---- wave reduction per row, lane 0 writes ----
    #pragma unroll
    for (int r = 0; r < ROWS_PER_WAVE; ++r) {
        float s0 = S0[r], s1 = S1[r];
        #pragma unroll
        for (int off = 32; off > 0; off >>= 1) {
            s0 += __shfl_xor(s0, off);
            s1 += __shfl_xor(s1, off);
        }
        if (lane == 0) out[b * NTOK + row0 + r] = cvo * (s1 / s0);
    }
}

extern "C" void kernel_launch(void* const* d_in, const int* in_sizes, int n_in,
                              void* d_out, int out_size, void* d_ws, size_t ws_size,
                              hipStream_t stream) {
    const float* x    = (const float*)d_in[0];
    const float* wq   = (const float*)d_in[1];
    const float* wk   = (const float*)d_in[2];
    const float* wv   = (const float*)d_in[3];
    const float* wout = (const float*)d_in[4];
    float* out = (float*)d_out;

    attn_collapsed_kernel<<<dim3(GRID), dim3(BLOCK), 0, stream>>>(
        x, wq, wk, wv, wout, out);
}